// Round 9
// baseline (2388.911 us; speedup 1.0000x reference)
//
#include <hip/hip_runtime.h>
#include <hip/hip_bf16.h>

#define DIM 64

// ---------------- dtype detection ----------------
// flags: [0]=u_f32 [1]=i_f32 [2]=w_f32 [3]=ui_i64 [4]=ii_i64
__global__ void k_detect(const unsigned short* __restrict__ ue,
                         const unsigned short* __restrict__ ie,
                         const unsigned short* __restrict__ we,
                         const unsigned int* __restrict__ uidx,
                         const unsigned int* __restrict__ iidx,
                         int* __restrict__ flags) {
  if (threadIdx.x != 0 || blockIdx.x != 0) return;
  auto isf32 = [](const unsigned short* p) {
    for (int i = 0; i < 256; ++i)
      if (((p[i] >> 7) & 0xFF) >= 142) return 1;  // f32 mantissa garbage as bf16
    return 0;
  };
  auto is64 = [](const unsigned int* p) {
    for (int i = 0; i < 64; ++i)
      if (p[2 * i + 1] != 0u) return 0;
    return 1;
  };
  flags[0] = isf32(ue);
  flags[1] = isf32(ie);
  flags[2] = isf32(we);
  flags[3] = is64(uidx);
  flags[4] = is64(iidx);
}

__device__ __forceinline__ int load_idx(const int* p, int e, int f64) {
  return f64 ? (int)((const long long*)p)[e] : p[e];
}

// ---------------- degree ----------------
__global__ void k_degree(const int* __restrict__ ui, const int* __restrict__ ii,
                         const int* __restrict__ flags,
                         int* __restrict__ deg, int E, int NU) {
  int e = blockIdx.x * blockDim.x + threadIdx.x;
  if (e >= E) return;
  atomicAdd(&deg[load_idx(ui, e, flags[3])], 1);
  atomicAdd(&deg[NU + load_idx(ii, e, flags[4])], 1);
}

__global__ void k_dinv(const int* __restrict__ deg, float* __restrict__ dinv, int N) {
  int i = blockIdx.x * blockDim.x + threadIdx.x;
  if (i < N) dinv[i] = rsqrtf((float)deg[i] + 1e-10f);
}

// ---------------- exclusive scan (3-phase) ----------------
__global__ void k_scan1(const int* __restrict__ deg, int* __restrict__ bsum, int N) {
  __shared__ int s[256];
  int i = blockIdx.x * 256 + threadIdx.x;
  s[threadIdx.x] = (i < N) ? deg[i] : 0;
  __syncthreads();
  for (int off = 128; off > 0; off >>= 1) {
    if (threadIdx.x < off) s[threadIdx.x] += s[threadIdx.x + off];
    __syncthreads();
  }
  if (threadIdx.x == 0) bsum[blockIdx.x] = s[0];
}

__global__ void k_scan2(int* __restrict__ bsum, int nb) {
  __shared__ int s[1024];
  int t = threadIdx.x;
  int v = (t < nb) ? bsum[t] : 0;
  s[t] = v;
  __syncthreads();
  for (int off = 1; off < 1024; off <<= 1) {
    int tmp = (t >= off) ? s[t - off] : 0;
    __syncthreads();
    s[t] += tmp;
    __syncthreads();
  }
  if (t < nb) bsum[t] = s[t] - v;  // exclusive
}

__global__ void k_scan3(const int* __restrict__ deg, const int* __restrict__ bsum,
                        int* __restrict__ row_ptr, int N) {
  __shared__ int s[256];
  int t = threadIdx.x;
  int i = blockIdx.x * 256 + t;
  int v = (i < N) ? deg[i] : 0;
  s[t] = v;
  __syncthreads();
  for (int off = 1; off < 256; off <<= 1) {
    int tmp = (t >= off) ? s[t - off] : 0;
    __syncthreads();
    s[t] += tmp;
    __syncthreads();
  }
  if (i < N) row_ptr[i] = bsum[blockIdx.x] + s[t] - v;
}

// ---------------- scatter edges into CSR (cols only) ----------------
__global__ void k_scatter(const int* __restrict__ ui, const int* __restrict__ ii,
                          const int* __restrict__ flags, const int* __restrict__ row_ptr,
                          int* __restrict__ cnt, int* __restrict__ cols, int E, int NU) {
  int e = blockIdx.x * blockDim.x + threadIdx.x;
  if (e >= E) return;
  int u = load_idx(ui, e, flags[3]);
  int it = NU + load_idx(ii, e, flags[4]);
  cols[row_ptr[u] + atomicAdd(&cnt[u], 1)] = it;
  cols[row_ptr[it] + atomicAdd(&cnt[it], 1)] = u;
}

// ---------------- fused SpMM + Linear + ReLU ----------------
// MODE 0: gather x (f32/bf16 per flags, split=NU) -> h1 bf16
// MODE 1: gather h_prev (bf16)                    -> h2 bf16
// MODE 2: gather h2 (bf16); FINAL f32 out[r] = (x[r]+h1[r]+h2[r]+h3)*0.25
template <int MODE>
__global__ __launch_bounds__(256) void k_layer(
    const int* __restrict__ row_ptr, const int* __restrict__ deg,
    const int* __restrict__ cols, const float* __restrict__ dinv,
    const void* __restrict__ xA, const void* __restrict__ xB, int split,
    const __hip_bfloat16* __restrict__ hprev,
    const void* __restrict__ Wbase, int layer, const int* __restrict__ flags,
    const __hip_bfloat16* __restrict__ h1row, const __hip_bfloat16* __restrict__ h2row,
    __hip_bfloat16* __restrict__ hout, float* __restrict__ fout, int N) {
  const int fu = flags[0];
  const int fi = flags[1];
  const int fw = flags[2];

  __shared__ float Wt[64 * 64];  // Wt[k*64 + d] = W[l][d][k]  (C-order source)
  for (int i = threadIdx.x; i < 64 * 64; i += 256) {
    float wv = fw ? ((const float*)Wbase)[layer * 4096 + i]
                  : __bfloat162float(((const __hip_bfloat16*)Wbase)[layer * 4096 + i]);
    int d = i >> 6, k = i & 63;
    Wt[(k << 6) + d] = wv;
  }
  __syncthreads();

  const int wave = threadIdx.x >> 6;
  const int lane = threadIdx.x & 63;
  const int stride = gridDim.x * 4;

  auto loadx = [&](int c) -> float {  // x[c][lane], per-input dtype
    if (c < split) {
      size_t o = (size_t)c * DIM + lane;
      return fu ? ((const float*)xA)[o]
                : __bfloat162float(((const __hip_bfloat16*)xA)[o]);
    } else {
      size_t o = (size_t)(c - split) * DIM + lane;
      return fi ? ((const float*)xB)[o]
                : __bfloat162float(((const __hip_bfloat16*)xB)[o]);
    }
  };

  for (int r = blockIdx.x * 4 + wave; r < N; r += stride) {
    const int start = row_ptr[r];
    const int end = start + deg[r];

    float sum = 0.f;
    auto gat = [&](int c) -> float {
      if constexpr (MODE == 0) return loadx(c);
      else return __bfloat162float(hprev[(size_t)c * DIM + lane]);
    };

    int e = start;
    for (; e + 4 <= end; e += 4) {
      int c0 = cols[e], c1 = cols[e + 1], c2 = cols[e + 2], c3 = cols[e + 3];
      float w0 = dinv[c0], w1 = dinv[c1], w2 = dinv[c2], w3 = dinv[c3];
      float v0 = gat(c0), v1 = gat(c1), v2 = gat(c2), v3 = gat(c3);
      sum += w0 * v0;
      sum += w1 * v1;
      sum += w2 * v2;
      sum += w3 * v3;
    }
    for (; e < end; ++e) {
      int c = cols[e];
      sum += dinv[c] * gat(c);
    }
    sum *= dinv[r];  // agg[r][lane]

    // lin[d] = sum_k agg[k] * W[d][k]; lane = d
    float lin = 0.f;
#pragma unroll
    for (int k = 0; k < 64; ++k) {
      float a = __shfl(sum, k);
      lin += a * Wt[(k << 6) + lane];
    }
    float hn = lin > 0.f ? lin : 0.f;

    size_t o = (size_t)r * DIM + lane;
    if constexpr (MODE == 2) {
      float xr = loadx(r);
      float h1v = __bfloat162float(h1row[o]);
      float h2v = __bfloat162float(h2row[o]);
      fout[o] = (xr + h1v + h2v + hn) * 0.25f;  // FLOAT32 output
    } else {
      hout[o] = __float2bfloat16(hn);
    }
  }
}

extern "C" void kernel_launch(void* const* d_in, const int* in_sizes, int n_in,
                              void* d_out, int out_size, void* d_ws, size_t ws_size,
                              hipStream_t stream) {
  const void* user_e = d_in[0];
  const void* item_e = d_in[1];
  const void* W = d_in[2];
  const int* ui = (const int*)d_in[3];
  const int* ii = (const int*)d_in[4];

  const int NU = in_sizes[0] / DIM;
  const int NI = in_sizes[1] / DIM;
  const int N = NU + NI;
  const int E = in_sizes[3];
  float* out = (float*)d_out;  // OUTPUT IS FLOAT32

  // Workspace ~66 MB (N=150k, E=3M)
  auto align = [](size_t x) { return (x + 255) & ~(size_t)255; };
  char* w = (char*)d_ws;
  size_t off = 0;
  int* deg = (int*)(w + off);      off += align((size_t)N * 4);
  int* cnt = (int*)(w + off);      off += align((size_t)N * 4);
  int* bsum = (int*)(w + off);     off += align((size_t)4096 * 4);
  int* flags = (int*)(w + off);    off += align(256);
  size_t meta_zero_bytes = off;
  int* row_ptr = (int*)(w + off);  off += align((size_t)N * 4);
  float* dinv = (float*)(w + off); off += align((size_t)N * 4);
  int* cols = (int*)(w + off);     off += align((size_t)2 * E * 4);
  __hip_bfloat16* h1 = (__hip_bfloat16*)(w + off); off += align((size_t)N * DIM * 2);
  __hip_bfloat16* h2 = (__hip_bfloat16*)(w + off); off += align((size_t)N * DIM * 2);
  (void)ws_size;

  hipMemsetAsync(d_ws, 0, meta_zero_bytes, stream);

  k_detect<<<1, 64, 0, stream>>>((const unsigned short*)user_e,
                                 (const unsigned short*)item_e,
                                 (const unsigned short*)W,
                                 (const unsigned int*)ui,
                                 (const unsigned int*)ii, flags);

  const int TPB = 256;
  k_degree<<<(E + TPB - 1) / TPB, TPB, 0, stream>>>(ui, ii, flags, deg, E, NU);
  k_dinv<<<(N + TPB - 1) / TPB, TPB, 0, stream>>>(deg, dinv, N);

  int nb = (N + 255) / 256;  // 586 for N=150000, must be <= 1024
  k_scan1<<<nb, 256, 0, stream>>>(deg, bsum, N);
  k_scan2<<<1, 1024, 0, stream>>>(bsum, nb);
  k_scan3<<<nb, 256, 0, stream>>>(deg, bsum, row_ptr, N);

  k_scatter<<<(E + TPB - 1) / TPB, TPB, 0, stream>>>(ui, ii, flags, row_ptr, cnt,
                                                     cols, E, NU);

  const int LGRID = 2048;
  k_layer<0><<<LGRID, 256, 0, stream>>>(row_ptr, deg, cols, dinv, user_e, item_e, NU,
                                        nullptr, W, 0, flags, nullptr, nullptr,
                                        h1, nullptr, N);
  k_layer<1><<<LGRID, 256, 0, stream>>>(row_ptr, deg, cols, dinv, user_e, item_e, NU,
                                        h1, W, 1, flags, nullptr, nullptr,
                                        h2, nullptr, N);
  k_layer<2><<<LGRID, 256, 0, stream>>>(row_ptr, deg, cols, dinv, user_e, item_e, NU,
                                        h2, W, 2, flags, h1, h2,
                                        nullptr, out, N);
}